// Round 1
// baseline (89.267 us; speedup 1.0000x reference)
//
#include <hip/hip_runtime.h>

#define NUM_Z 100
#define NUM_G 512
#define DIM 64   // features per node; DIM/4 = 16 float4 quads

// ---- kernel 1: per-graph node counts ----
__global__ void anp_count_kernel(const int* __restrict__ batch, int n,
                                 int* __restrict__ counts) {
    int i = blockIdx.x * blockDim.x + threadIdx.x;
    if (i < n) atomicAdd(&counts[batch[i]], 1);
}

// ---- kernel 2: reciprocal of counts ----
__global__ void anp_inv_kernel(const int* __restrict__ counts,
                               float* __restrict__ inv) {
    int g = blockIdx.x * blockDim.x + threadIdx.x;
    if (g < NUM_G) {
        int c = counts[g];
        inv[g] = 1.0f / (float)(c > 1 ? c : 1);
    }
}

// ---- kernel 3: scaled scatter-add into (graph, z) bins ----
__global__ void anp_scatter_kernel(const float4* __restrict__ feat,   // [N*16] quads
                                   const int* __restrict__ z,
                                   const int* __restrict__ batch,
                                   const float* __restrict__ inv,
                                   float* __restrict__ pooled,        // [G*100*64]
                                   int n) {
    int t = blockIdx.x * blockDim.x + threadIdx.x;
    int i = t >> 4;          // node index
    int q = t & 15;          // which float4 quad of the 64-dim row
    if (i >= n) return;
    int g = batch[i];
    int key = g * NUM_Z + (z[i] - 1);
    float s = inv[g];
    float4 v = feat[i * 16 + q];
    float* dst = pooled + (size_t)key * DIM + q * 4;
    atomicAdd(dst + 0, v.x * s);
    atomicAdd(dst + 1, v.y * s);
    atomicAdd(dst + 2, v.z * s);
    atomicAdd(dst + 3, v.w * s);
}

extern "C" void kernel_launch(void* const* d_in, const int* in_sizes, int n_in,
                              void* d_out, int out_size, void* d_ws, size_t ws_size,
                              hipStream_t stream) {
    const float* feat  = (const float*)d_in[0];   // out: [N, 64] fp32
    const int*   z     = (const int*)d_in[1];     // z_rv: [N] int32 in [1,100]
    const int*   batch = (const int*)d_in[2];     // x_rv_batch: [N] int32 sorted

    float* pooled = (float*)d_out;                // [512 * 6400] fp32
    int n = in_sizes[0] / DIM;                    // 50000 nodes

    int*   counts = (int*)d_ws;                          // 512 ints
    float* inv    = (float*)((char*)d_ws + NUM_G * sizeof(int)); // 512 floats

    // zero output and counts each call (harness does not re-poison between replays)
    hipMemsetAsync(d_out, 0, (size_t)out_size * sizeof(float), stream);
    hipMemsetAsync(counts, 0, NUM_G * sizeof(int), stream);

    anp_count_kernel<<<(n + 255) / 256, 256, 0, stream>>>(batch, n, counts);
    anp_inv_kernel<<<(NUM_G + 255) / 256, 256, 0, stream>>>(counts, inv);

    int threads = n * (DIM / 4);                  // one thread per float4 quad
    anp_scatter_kernel<<<(threads + 255) / 256, 256, 0, stream>>>(
        (const float4*)feat, z, batch, inv, pooled, n);
}

// Round 2
// 32.301 us; speedup vs baseline: 2.7636x; 2.7636x over previous
//
#include <hip/hip_runtime.h>

#define NUM_Z 100
#define NUM_G 512
#define DIM   64            // features per node
#define BIN_FLOATS (NUM_Z * DIM)   // 6400 floats = 25.6 KB LDS per graph

// ---- kernel 1: per-graph start offsets from the SORTED batch array ----
// starts[g] = first node index with batch id >= g; starts[NUM_G] = n.
__global__ void anp_starts_kernel(const int* __restrict__ batch, int n,
                                  int* __restrict__ starts) {
    int i = blockIdx.x * blockDim.x + threadIdx.x;
    if (i >= n) return;
    int cur  = batch[i];
    int prev = (i == 0) ? -1 : batch[i - 1];
    for (int g = prev + 1; g <= cur; ++g) starts[g] = i;   // first occurrence wins
    if (i == n - 1)
        for (int g = cur + 1; g <= NUM_G; ++g) starts[g] = n;  // trailing empties
}

// ---- kernel 2: one block per graph; LDS accumulate, exclusive global write ----
__global__ __launch_bounds__(256) void anp_pool_kernel(
    const float* __restrict__ feat,   // [N, 64] fp32
    const int*   __restrict__ z,      // [N] in [1,100]
    const int*   __restrict__ starts, // [G+1]
    float*       __restrict__ pooled) // [G, 100*64]
{
    __shared__ float acc[BIN_FLOATS];
    const int g   = blockIdx.x;
    const int tid = threadIdx.x;

    // zero the LDS tile (block exclusively owns graph g's output slice)
    for (int j = tid; j < BIN_FLOATS; j += 256) acc[j] = 0.0f;

    const int start = starts[g];
    const int end   = starts[g + 1];
    __syncthreads();

    const int wave = tid >> 6;
    const int lane = tid & 63;
    const int sub  = lane >> 4;   // 0..3: which node of the wave's quad
    const int q    = lane & 15;   // which float4 of the 64-dim row

    // each wave consumes 4 nodes per iteration; block consumes 16
    for (int base = start + wave * 4; base < end; base += 16) {
        const int i = base + sub;
        if (i < end) {
            const int zb = z[i] - 1;                       // uniform per 16-lane group
            const float4 v = *(const float4*)(feat + (size_t)i * DIM + q * 4);
            float* dst = &acc[zb * DIM + q * 4];
            atomicAdd(dst + 0, v.x);    // ds_add_f32: intra-block only, no L2 traffic
            atomicAdd(dst + 1, v.y);
            atomicAdd(dst + 2, v.z);
            atomicAdd(dst + 3, v.w);
        }
    }
    __syncthreads();

    // scale by 1/count at writeout (count = segment length; no count kernel needed)
    const int cnt = end - start;
    const float s = 1.0f / (float)(cnt > 1 ? cnt : 1);
    float4* outv = (float4*)(pooled + (size_t)g * BIN_FLOATS);
    const float4* accv = (const float4*)acc;
    for (int j = tid; j < BIN_FLOATS / 4; j += 256) {
        float4 a = accv[j];
        a.x *= s; a.y *= s; a.z *= s; a.w *= s;
        outv[j] = a;                   // coalesced float4, exactly-once coverage
    }
}

extern "C" void kernel_launch(void* const* d_in, const int* in_sizes, int n_in,
                              void* d_out, int out_size, void* d_ws, size_t ws_size,
                              hipStream_t stream) {
    const float* feat  = (const float*)d_in[0];
    const int*   z     = (const int*)d_in[1];
    const int*   batch = (const int*)d_in[2];   // sorted graph ids
    float* pooled = (float*)d_out;
    const int n = in_sizes[0] / DIM;            // 50000

    int* starts = (int*)d_ws;                   // (NUM_G + 1) ints, fully overwritten

    anp_starts_kernel<<<(n + 255) / 256, 256, 0, stream>>>(batch, n, starts);
    anp_pool_kernel<<<NUM_G, 256, 0, stream>>>(feat, z, starts, pooled);
}

// Round 3
// 27.890 us; speedup vs baseline: 3.2007x; 1.1581x over previous
//
#include <hip/hip_runtime.h>

#define NUM_Z 100
#define NUM_G 512
#define DIM   64
#define BIN_FLOATS (NUM_Z * DIM)   // 6400 floats = 25.6 KB LDS tile
#define THREADS 1024               // 16 waves; 2 blocks/CU -> 32 waves/CU

// Wave-cooperative 64-ary lower_bound: first index i with arr[i] >= target.
// ~3 gather rounds for n=50000 (50000 -> 781 -> 12 -> 0). k from __ballot is
// wave-uniform, so lo/len stay scalar.
__device__ __forceinline__ int lower_bound_wave(const int* __restrict__ arr, int n,
                                                int target, int lane) {
    int lo = 0, len = n;                 // invariant: arr[lo-1] < target, answer in [lo, lo+len]
    while (len > 0) {
        int step = (len + 63) >> 6;      // >= 1
        int idx  = lo + lane * step;
        int v    = (idx < n) ? arr[idx] : 0x7fffffff;
        unsigned long long m = __ballot(v < target);
        int k = (int)__popcll(m);        // contiguous from lane 0 (sorted array)
        if (k == 0) break;               // arr[lo] >= target -> answer = lo
        int rem = k * step; if (rem > len) rem = len;
        int hi  = lo + rem;              // answer <= hi
        lo += (k - 1) * step + 1;        // arr[new_lo - 1] < target
        len = hi - lo;
    }
    return lo;
}

__global__ __launch_bounds__(THREADS) void anp_fused_kernel(
    const float4* __restrict__ feat,   // [N*16] float4 quads of the [N,64] features
    const int*    __restrict__ z,      // [N] in [1,100]
    const int*    __restrict__ batch,  // [N] sorted graph ids
    float*        __restrict__ pooled, // [G, 100*64]
    int n)
{
    __shared__ float acc[BIN_FLOATS];
    __shared__ int   sb[2];            // start, end of this graph's node segment
    const int g    = blockIdx.x;
    const int tid  = threadIdx.x;
    const int wave = tid >> 6;
    const int lane = tid & 63;

    // zero the LDS tile (all 16 waves, float4-wide)
    float4* accv = (float4*)acc;
    for (int j = tid; j < BIN_FLOATS / 4; j += THREADS)
        accv[j] = make_float4(0.f, 0.f, 0.f, 0.f);

    // waves 0/1 find the segment bounds while others finish zeroing
    if (wave < 2) {
        int r = lower_bound_wave(batch, n, g + wave, lane);
        if (lane == 0) sb[wave] = r;
    }
    __syncthreads();
    const int start = sb[0];
    const int end   = sb[1];

    // each wave: 4 nodes/iter (16 lanes per node, float4 per lane); block: 64 nodes/iter
    const int sub = lane >> 4;         // which of the wave's 4 nodes
    const int q   = lane & 15;         // which float4 quad of the 64-dim row
    for (int base = start + wave * 4; base < end; base += THREADS / 16) {
        const int i = base + sub;
        if (i < end) {
            const int zb = z[i] - 1;                  // uniform per 16-lane group
            const float4 v = feat[(size_t)i * 16 + q];
            float* dst = &acc[zb * DIM + q * 4];
            atomicAdd(dst + 0, v.x);   // ds_add_f32, intra-block only
            atomicAdd(dst + 1, v.y);
            atomicAdd(dst + 2, v.z);
            atomicAdd(dst + 3, v.w);
        }
    }
    __syncthreads();

    // scale by 1/count and stream out (exactly-once coverage, coalesced float4)
    const int cnt = end - start;
    const float s = 1.0f / (float)(cnt > 1 ? cnt : 1);
    float4* outv = (float4*)(pooled + (size_t)g * BIN_FLOATS);
    for (int j = tid; j < BIN_FLOATS / 4; j += THREADS) {
        float4 a = accv[j];
        a.x *= s; a.y *= s; a.z *= s; a.w *= s;
        outv[j] = a;
    }
}

extern "C" void kernel_launch(void* const* d_in, const int* in_sizes, int n_in,
                              void* d_out, int out_size, void* d_ws, size_t ws_size,
                              hipStream_t stream) {
    const float* feat  = (const float*)d_in[0];
    const int*   z     = (const int*)d_in[1];
    const int*   batch = (const int*)d_in[2];
    float* pooled = (float*)d_out;
    const int n = in_sizes[0] / DIM;   // 50000

    anp_fused_kernel<<<NUM_G, THREADS, 0, stream>>>(
        (const float4*)feat, z, batch, pooled, n);
}

// Round 4
// 17.538 us; speedup vs baseline: 5.0899x; 1.5903x over previous
//
#include <hip/hip_runtime.h>

#define NUM_Z 100
#define NUM_G 512
#define DIM   64
#define THREADS 1024
#define CHUNK 1024          // z values staged per pass (cnt ~97, so 1 pass)

// Wave-cooperative 64-ary lower_bound: first i with arr[i] >= target.
__device__ __forceinline__ int lower_bound_wave(const int* __restrict__ arr, int n,
                                                int target, int lane) {
    int lo = 0, len = n;
    while (len > 0) {
        int step = (len + 63) >> 6;
        int idx  = lo + lane * step;
        int v    = (idx < n) ? arr[idx] : 0x7fffffff;
        unsigned long long m = __ballot(v < target);
        int k = (int)__popcll(m);
        if (k == 0) break;
        int rem = k * step; if (rem > len) rem = len;
        int hi  = lo + rem;
        lo += (k - 1) * step + 1;
        len = hi - lo;
    }
    return lo;
}

// One block per graph. 64 groups of 16 lanes; groups 0..49 each OWN bins
// {2g, 2g+1}: scan the graph's z list (LDS broadcast), pull matching feature
// rows, accumulate in registers, store once. No LDS accumulator, no atomics.
__global__ __launch_bounds__(THREADS) void anp_scan_kernel(
    const float4* __restrict__ feat,   // [N*16] quads of [N,64] features
    const int*    __restrict__ z,      // [N] in [1,100]
    const int*    __restrict__ batch,  // [N] sorted graph ids
    float*        __restrict__ pooled, // [G, 100*64]
    int n)
{
    __shared__ int zs[CHUNK];
    __shared__ int sb[2];
    const int g    = blockIdx.x;
    const int tid  = threadIdx.x;
    const int wave = tid >> 6;
    const int lane = tid & 63;

    if (wave < 2) {
        int r = lower_bound_wave(batch, n, g + wave, lane);
        if (lane == 0) sb[wave] = r;
    }
    __syncthreads();
    const int start = sb[0];
    const int end   = sb[1];
    const int cnt   = end - start;

    const int grp = tid >> 4;          // 0..63; active groups: 0..49
    const int q   = tid & 15;          // which float4 quad of the 64-dim row
    const int b0  = 2 * grp;
    const int b1  = b0 + 1;
    float4 a0 = make_float4(0.f, 0.f, 0.f, 0.f);
    float4 a1 = make_float4(0.f, 0.f, 0.f, 0.f);

    for (int chunk = start; chunk < end; chunk += CHUNK) {
        const int m = min(CHUNK, end - chunk);
        __syncthreads();                               // zs reuse guard
        zs[tid] = (chunk + tid < end) ? (z[chunk + tid] - 1) : -1;  // coalesced
        __syncthreads();

        if (grp < 50) {
            const int4* zs4 = (const int4*)zs;
            const int m4 = (m + 3) >> 2;               // padded with -1: no match
            #pragma unroll 4
            for (int t = 0; t < m4; ++t) {
                int4 zq = zs4[t];                      // LDS broadcast, 4 z's
                const int jb = chunk + t * 4;
                #define ANP_PROC(comp, off)                                         \
                    { int zb = (comp);                                              \
                      if (zb == b0 || zb == b1) {                                   \
                          float4 v = feat[(size_t)(jb + (off)) * 16 + q];           \
                          if (zb == b0) { a0.x += v.x; a0.y += v.y;                 \
                                          a0.z += v.z; a0.w += v.w; }               \
                          else          { a1.x += v.x; a1.y += v.y;                 \
                                          a1.z += v.z; a1.w += v.w; } } }
                ANP_PROC(zq.x, 0) ANP_PROC(zq.y, 1) ANP_PROC(zq.z, 2) ANP_PROC(zq.w, 3)
                #undef ANP_PROC
            }
        }
    }

    if (grp < 50) {
        const float s = 1.0f / (float)(cnt > 1 ? cnt : 1);
        float4* outv = (float4*)(pooled + (size_t)g * (NUM_Z * DIM));
        // group writes bins b0,b1: 16 lanes x 16B = 256B contiguous each,
        // wave covers 8 consecutive bins -> 2KB contiguous stores
        outv[b0 * 16 + q] = make_float4(a0.x * s, a0.y * s, a0.z * s, a0.w * s);
        outv[b1 * 16 + q] = make_float4(a1.x * s, a1.y * s, a1.z * s, a1.w * s);
    }
}

extern "C" void kernel_launch(void* const* d_in, const int* in_sizes, int n_in,
                              void* d_out, int out_size, void* d_ws, size_t ws_size,
                              hipStream_t stream) {
    const float* feat  = (const float*)d_in[0];
    const int*   z     = (const int*)d_in[1];
    const int*   batch = (const int*)d_in[2];
    float* pooled = (float*)d_out;
    const int n = in_sizes[0] / DIM;   // 50000

    anp_scan_kernel<<<NUM_G, THREADS, 0, stream>>>(
        (const float4*)feat, z, batch, pooled, n);
}

// Round 5
// 12.148 us; speedup vs baseline: 7.3485x; 1.4438x over previous
//
#include <hip/hip_runtime.h>

#define NUM_Z 100
#define NUM_G 512
#define DIM   64
#define THREADS 1024
#define CHUNK 1024   // nodes per in-block pass (cnt ~97 -> 1 pass)

// Wave-cooperative 64-ary lower_bound: first i with arr[i] >= target.
__device__ __forceinline__ int lower_bound_wave(const int* __restrict__ arr, int n,
                                                int target, int lane) {
    int lo = 0, len = n;
    while (len > 0) {
        int step = (len + 63) >> 6;
        int idx  = lo + lane * step;
        int v    = (idx < n) ? arr[idx] : 0x7fffffff;
        unsigned long long m = __ballot(v < target);
        int k = (int)__popcll(m);
        if (k == 0) break;
        int rem = k * step; if (rem > len) rem = len;
        int hi  = lo + rem;
        lo += (k - 1) * step + 1;
        len = hi - lo;
    }
    return lo;
}

// One block per graph. In-LDS counting sort of the graph's nodes by z bin,
// then each 16-lane group gathers its two bins' contiguous node list with
// bulk-issued independent float4 loads (no atomics on float data, no
// divergent load-inside-scan).
__global__ __launch_bounds__(THREADS) void anp_sort_kernel(
    const float4* __restrict__ feat,   // [N*16] quads of [N,64] features
    const int*    __restrict__ z,      // [N] in [1,100]
    const int*    __restrict__ batch,  // [N] sorted graph ids
    float*        __restrict__ pooled, // [G, 100*64]
    int n)
{
    __shared__ int hist[128];               // per-bin counts (padded to 128)
    __shared__ int scan_tmp[128];           // inclusive scan of hist
    __shared__ int pref[NUM_Z + 1];         // exclusive bin offsets
    __shared__ int cursor[NUM_Z];           // scatter cursors
    __shared__ unsigned short idx_sorted[CHUNK];  // node idx | parity<<15, sorted by z
    __shared__ int sb[2];
    __shared__ int wtot;                    // wave-0 scan total

    const int g    = blockIdx.x;
    const int tid  = threadIdx.x;
    const int wave = tid >> 6;
    const int lane = tid & 63;
    const int grp  = tid >> 4;              // 0..63; active gather groups: 0..49
    const int q    = tid & 15;              // float4 quad of the 64-dim row
    const int b0   = 2 * grp;               // group owns bins b0, b0+1

    if (wave < 2) {
        int r = lower_bound_wave(batch, n, g + wave, lane);
        if (lane == 0) sb[wave] = r;
    }
    __syncthreads();
    const int start = sb[0];
    const int end   = sb[1];
    const int cnt   = end - start;

    float4 a0 = make_float4(0.f, 0.f, 0.f, 0.f);
    float4 a1 = make_float4(0.f, 0.f, 0.f, 0.f);

    for (int cs = start; cs < end; cs += CHUNK) {
        const int m = min(CHUNK, end - cs);

        if (tid < 128) hist[tid] = 0;
        __syncthreads();

        int zv = 0;
        if (tid < m) {
            zv = z[cs + tid] - 1;           // coalesced
            atomicAdd(&hist[zv], 1);        // LDS int atomic
        }
        __syncthreads();

        // 2-wave shfl inclusive scan over the 128 hist entries
        if (wave < 2) {
            int e = hist[(wave << 6) + lane];
            #pragma unroll
            for (int d = 1; d < 64; d <<= 1) {
                int t = __shfl_up(e, d, 64);
                if (lane >= d) e += t;
            }
            scan_tmp[(wave << 6) + lane] = e;
            if (wave == 0 && lane == 63) wtot = e;
        }
        __syncthreads();

        if (tid <= NUM_Z) {
            int v = (tid == 0) ? 0
                  : scan_tmp[tid - 1] + ((tid - 1) >= 64 ? wtot : 0);
            pref[tid] = v;
            if (tid < NUM_Z) cursor[tid] = v;
        }
        __syncthreads();

        if (tid < m) {
            int p = atomicAdd(&cursor[zv], 1);
            idx_sorted[p] = (unsigned short)(tid | ((zv & 1) << 15));
        }
        __syncthreads();

        // gather: group's two bins are contiguous in idx_sorted
        if (grp < 50) {
            const int off = pref[b0];
            const int c   = pref[b0 + 2] - off;
            for (int base = 0; base < c; base += 16) {
                const int nb = min(16, c - base);
                // 16 lanes bulk-read up to 16 sorted indices in one LDS access
                int myraw = (q < nb) ? (int)idx_sorted[off + base + q] : 0;
                #pragma unroll 4
                for (int j = 0; j < nb; ++j) {
                    int raw  = __shfl(myraw, ((lane >> 4) << 4) + j, 64);
                    int nd   = raw & 0x7fff;
                    float pm = (float)(raw >> 15);      // 0 -> bin b0, 1 -> bin b1
                    float4 v = feat[(size_t)(cs + nd) * 16 + q];
                    float m0 = 1.0f - pm;
                    a0.x = fmaf(v.x, m0, a0.x); a0.y = fmaf(v.y, m0, a0.y);
                    a0.z = fmaf(v.z, m0, a0.z); a0.w = fmaf(v.w, m0, a0.w);
                    a1.x = fmaf(v.x, pm, a1.x); a1.y = fmaf(v.y, pm, a1.y);
                    a1.z = fmaf(v.z, pm, a1.z); a1.w = fmaf(v.w, pm, a1.w);
                }
            }
        }
        __syncthreads();   // idx_sorted/pref reuse guard for next chunk
    }

    if (grp < 50) {
        const float s = 1.0f / (float)(cnt > 1 ? cnt : 1);
        float4* outv = (float4*)(pooled + (size_t)g * (NUM_Z * DIM));
        outv[(b0 + 0) * 16 + q] = make_float4(a0.x*s, a0.y*s, a0.z*s, a0.w*s);
        outv[(b0 + 1) * 16 + q] = make_float4(a1.x*s, a1.y*s, a1.z*s, a1.w*s);
    }
}

extern "C" void kernel_launch(void* const* d_in, const int* in_sizes, int n_in,
                              void* d_out, int out_size, void* d_ws, size_t ws_size,
                              hipStream_t stream) {
    const float* feat  = (const float*)d_in[0];
    const int*   z     = (const int*)d_in[1];
    const int*   batch = (const int*)d_in[2];
    float* pooled = (float*)d_out;
    const int n = in_sizes[0] / DIM;   // 50000

    anp_sort_kernel<<<NUM_G, THREADS, 0, stream>>>(
        (const float4*)feat, z, batch, pooled, n);
}